// Round 2
// baseline (172.459 us; speedup 1.0000x reference)
//
#include <hip/hip_runtime.h>
#include <float.h>

// Problem constants (fixed by reference: B=8, D=64, H=64, W=64, K=8192)
constexpr int KCODES = 8192;
constexpr int DDIM   = 64;
constexpr int NTOK   = 32768;
constexpr int MT     = 32;                 // tokens per WG (2 sets x 16)
constexpr int KC     = 64;                 // codes per chunk
constexpr int NCH    = KCODES / KC;        // 128 chunks
constexpr int CBCHUNK = KC * DDIM * 2;     // 8192 B (64 codes x 64 d x bf16, hi only)

constexpr int RQ   = 4;                    // LDS staging ring depth (per wave)
constexpr int SLOT = 2304;                 // 2 KB A-frags + 256 B hn block

typedef short v8s __attribute__((ext_vector_type(8)));
typedef float v4f __attribute__((ext_vector_type(4)));

static __device__ __forceinline__ unsigned short f2bf(float f) {
  union { float f; unsigned u; } v; v.f = f;
  return (unsigned short)((v.u + 0x7fffu + ((v.u >> 16) & 1u)) >> 16);  // RNE
}

// async global->LDS DMA: dest = wave-uniform LDS base + lane*size (m104);
// source is per-lane. Tracked by vmcnt.
static __device__ __forceinline__ void dma16(const void* g, void* l) {
  __builtin_amdgcn_global_load_lds(
      (const __attribute__((address_space(1))) void*)g,
      (__attribute__((address_space(3))) void*)l, 16, 0, 0);
}
static __device__ __forceinline__ void dma4(const void* g, void* l) {
  __builtin_amdgcn_global_load_lds(
      (const __attribute__((address_space(1))) void*)g,
      (__attribute__((address_space(3))) void*)l, 4, 0, 0);
}

// ---- fused prep: bf16 hi codebook, FRAGMENT-LINEAR for mfma_16x16x32_bf16
// A-operand (A[m=lane&15][k=(lane>>4)*8+j]), + biased half-norms
// hn[k] = 0.5*||c_k||^2 + 2.0 (bias keeps phase-1 scores positive -> fp32
// bit pattern monotone for the packed-key argmin; scores land in [~0.7,~4.5]).
// Per chunk c: byte off = c*8192 + g*2048 + ks*1024 + lane*16 + j*2.
__global__ __launch_bounds__(256) void prep_kernel(
    const float* __restrict__ cb, unsigned short* __restrict__ wcb,
    float* __restrict__ hn) {
  const int c = blockIdx.x;                 // chunk 0..127
  const int tid = threadIdx.x;
  const int g = tid >> 6, lane = tid & 63;
  const int quad = lane >> 4, col = lane & 15;
  const int code = c * KC + g * 16 + col;
  const float* src = cb + (size_t)code * DDIM;
  float sq = 0.f;
#pragma unroll
  for (int ks = 0; ks < 2; ++ks) {
    v8s hi;
#pragma unroll
    for (int j = 0; j < 8; ++j) {
      const float x = src[ks * 32 + quad * 8 + j];
      sq += x * x;
      hi[j] = (short)f2bf(x);
    }
    const size_t b0 = ((size_t)c * CBCHUNK + g * 2048 + ks * 1024 + lane * 16) / 2;
    *reinterpret_cast<v8s*>(wcb + b0) = hi;
  }
  sq += __shfl_xor(sq, 16);
  sq += __shfl_xor(sq, 32);
  if (quad == 0) hn[code] = 0.5f * sq + 2.0f;
}

// Phase 1 (SCREEN): hi-only bf16 MFMA, score ~= hn - xh.ch.
//   Screening error e = xl.c + xh.cl: RMS ~2.5e-4, |e| <= ~2.8e-3 at 11
//   sigma. A-frags staged via async global_load_lds into a PER-WAVE LDS
//   ring (depth 4, 3 DMA ops/chunk, counted s_waitcnt vmcnt(9), no
//   barriers: each wave stages and reads only its own slice, so there is
//   no cross-wave dependency in the main loop). 4 WG/CU. Branchless
//   packed-key top-2 per (lane,set) cell: key = (score-bits & ~511) |
//   (it*4 + r); floor quantization <= 512 ulp <= 2.4e-4.
// Phase 2: fast path when unique candidate within smin+8e-3. Proof: for any
//   candidate with stored > lim: true > stored - e > smin + 8e-3 - 2.8e-3;
//   smin >= true_min - e - 2.4e-4 -> true - true_min > 8e-3 - 5.6e-3 -
//   2.4e-4 > 2e-3 >> numpy's ulp(64) ~1.5e-5 quantization -> numpy cannot
//   prefer it. A numpy-winner distinct from the approx winner is itself
//   within lim -> cnt >= 2 -> refine. Refine = numpy-fp32-faithful decision
//   (pairwise-8 sums, D=fl(fl(S-2p)+N), correctly-rounded-fp64 p,
//   tie -> lowest index) — identical to all passing rounds.
__global__ __launch_bounds__(256, 4) void vq_kernel(
    const float* __restrict__ ze, const float* __restrict__ cb,
    const float* __restrict__ hn, const unsigned short* __restrict__ wcb,
    float* __restrict__ out) {
  // Per-wave staging ring: wave wv owns smem[wv*RQ*SLOT .. +RQ*SLOT).
  // Epilogue arrays alias the same LDS after a drain + barrier.
  __shared__ __align__(16) char smem[4 * RQ * SLOT];   // 36864 B

  const int tid = threadIdx.x, lane = tid & 63, wv = tid >> 6;
  const int col = lane & 15, quad = lane >> 4;
  const int t0 = blockIdx.x * MT;
  const int bb = t0 >> 12, hw0 = t0 & 4095;   // 4096 % 32 == 0: one batch per WG
  const float* zb = ze + (size_t)bb * (DDIM * 4096) + hw0;

  // ---- B-frags: 2 sets x 16 tokens, negated bf16-hi, in registers.
  // B[k=(lane>>4)*8+j][n=lane&15]; token = s*16 + col; d = ks*32 + quad*8 + j.
  v8s nxh[2][2];
#pragma unroll
  for (int s = 0; s < 2; ++s) {
    const int mtok = s * 16 + col;
#pragma unroll
    for (int ks = 0; ks < 2; ++ks) {
#pragma unroll
      for (int j = 0; j < 8; ++j) {
        const int d = ks * 32 + quad * 8 + j;
        nxh[s][ks][j] = (short)f2bf(-zb[(size_t)d * 4096 + mtok]);
      }
    }
  }

  char* wbase = smem + wv * (RQ * SLOT);
  const char* wsrc = (const char*)wcb + wv * 2048 + lane * 16;
  const int hoff = wv * 64 + quad * 16;     // byte off of this cell's hv in hn block

  // Stage chunk -> slot: 2x 16B-wide A DMAs (2 KB) + 1x 4B-wide hn DMA (256 B).
  auto stage = [&](int chunk, int slot) {
    const char* src = wsrc + (size_t)chunk * CBCHUNK;
    char* dst = wbase + slot * SLOT;
    dma16(src, dst);
    dma16(src + 1024, dst + 1024);
    dma4((const char*)(hn + chunk * KC) + lane * 4, dst + 2048);
  };

  unsigned m1[2] = {0xFFFFFFFFu, 0xFFFFFFFFu};   // packed running top-2 keys
  unsigned m2[2] = {0xFFFFFFFFu, 0xFFFFFFFFu};

  auto compute = [&](const v8s (&A)[2], const v4f hv, int it) {
    v4f acc[2];
#pragma unroll
    for (int s = 0; s < 2; ++s) acc[s] = hv;
#pragma unroll
    for (int s = 0; s < 2; ++s)
      acc[s] = __builtin_amdgcn_mfma_f32_16x16x32_bf16(A[0], nxh[s][0], acc[s], 0, 0, 0);
#pragma unroll
    for (int s = 0; s < 2; ++s)
      acc[s] = __builtin_amdgcn_mfma_f32_16x16x32_bf16(A[1], nxh[s][1], acc[s], 0, 0, 0);

    const unsigned base9 = (unsigned)(it * 4);   // 9-bit cell-local index base
#pragma unroll
    for (int s = 0; s < 2; ++s) {
      unsigned k0 = (__float_as_uint(acc[s][0]) & ~511u) | (base9 + 0);
      unsigned k1 = (__float_as_uint(acc[s][1]) & ~511u) | (base9 + 1);
      unsigned k2 = (__float_as_uint(acc[s][2]) & ~511u) | (base9 + 2);
      unsigned k3 = (__float_as_uint(acc[s][3]) & ~511u) | (base9 + 3);
      const unsigned km = min(min(k0, k1), min(k2, k3));
      const unsigned old1 = m1[s];
      m1[s] = min(old1, km);
      m2[s] = min(m2[s], max(old1, km));   // branchless 2nd-best
    }
  };

  // ---- airtight vmcnt ledger: drain ze-prologue loads before first stage.
  asm volatile("s_waitcnt vmcnt(0)" ::: "memory");
  __builtin_amdgcn_sched_barrier(0);

#pragma unroll
  for (int r = 0; r < RQ; ++r) stage(r, r);   // 12 DMAs in flight

  for (int it = 0; it < NCH; ++it) {
    const int slot = it & (RQ - 1);
    // Wait until chunk `it`'s 3 DMAs landed (12 outstanding -> <= 9).
    asm volatile("s_waitcnt vmcnt(9)" ::: "memory");
    __builtin_amdgcn_sched_barrier(0);

    v8s A[2]; v4f hv;
    {
      const char* b = wbase + slot * SLOT;
      A[0] = *reinterpret_cast<const v8s*>(b + lane * 16);
      A[1] = *reinterpret_cast<const v8s*>(b + 1024 + lane * 16);
      hv   = *reinterpret_cast<const v4f*>(b + 2048 + hoff);
    }
    compute(A, hv, it);

    // ds_reads of this slot fully retired before the DMA overwrite lands.
    asm volatile("s_waitcnt lgkmcnt(0)" ::: "memory");
    __builtin_amdgcn_sched_barrier(0);
    stage((it + RQ) & (NCH - 1), slot);   // wraps at tail: redundant, never read
  }

  // Drain in-flight DMAs, then all waves quiesce before aliasing LDS.
  asm volatile("s_waitcnt vmcnt(0)" ::: "memory");
  __syncthreads();

  float (*c_s1)[MT] = (float (*)[MT])(smem);            // 2 KB
  float (*c_s2)[MT] = (float (*)[MT])(smem + 2048);     // 2 KB
  int   (*c_i1)[MT] = (int (*)[MT])(smem + 4096);       // 2 KB
  int   (*c_i2)[MT] = (int (*)[MT])(smem + 6144);       // 2 KB
  int*   widx       = (int*)(smem + 8192);              // 128 B

  // ---- surface per-cell top-2 (cell = wv*4+quad; 16 cells x 512 codes) ----
  {
    const int cell = wv * 4 + quad;
#pragma unroll
    for (int s = 0; s < 2; ++s) {
      const int m = s * 16 + col;
      const unsigned K1 = m1[s], K2 = m2[s];
      c_s1[cell][m] = __uint_as_float(K1 & ~511u);
      c_s2[cell][m] = __uint_as_float(K2 & ~511u);
      // decode: local = it*4 + r -> code = it*64 + wv*16 + quad*4 + r
      c_i1[cell][m] = (int)((K1 & 511u) >> 2) * KC + wv * 16 + quad * 4 + (int)(K1 & 3u);
      c_i2[cell][m] = (int)((K2 & 511u) >> 2) * KC + wv * 16 + quad * 4 + (int)(K2 & 3u);
    }
  }
  __syncthreads();

  // ---- phase 2: fast path or numpy-faithful refine ----
  if (tid < MT) {
#pragma clang fp contract(off)   // numpy: separate mul then add; no FMA
    const int m = tid;

    float smin = FLT_MAX; int fidx = 0x7fffffff;
    for (int c = 0; c < 16; ++c) {
      const float a = c_s1[c][m];
      if (a < smin) { smin = a; fidx = c_i1[c][m]; }
    }
    const float lim = smin + 8e-3f;   // covers 2*e_screen(2.8e-3) + key floor
                                      // 2.4e-4 + numpy noise, ~1.4x slack
    int cnt = 0;
    for (int c = 0; c < 16; ++c) {
      cnt += (c_s1[c][m] <= lim);
      cnt += (c_s2[c][m] <= lim);
    }

    int besti;
    if (cnt == 1) {
      besti = fidx;   // unique in-margin candidate: approx argmin == numpy argmin
    } else {
      const float* xz = zb + m;
      float xm[DDIM];
      for (int d = 0; d < DDIM; ++d) xm[d] = xz[(size_t)d * 4096];

      float r[8];
      for (int j = 0; j < 8; ++j) r[j] = xm[j] * xm[j];
      for (int i = 8; i < DDIM; i += 8)
        for (int j = 0; j < 8; ++j) r[j] += xm[i + j] * xm[i + j];
      const float S = ((r[0] + r[1]) + (r[2] + r[3])) + ((r[4] + r[5]) + (r[6] + r[7]));

      float bestD = FLT_MAX;
      besti = 0x7fffffff;
      for (int c = 0; c < 16; ++c) {
        for (int h = 0; h < 2; ++h) {
          const float sp = h ? c_s2[c][m] : c_s1[c][m];
          if (sp > lim) continue;
          const int idx = h ? c_i2[c][m] : c_i1[c][m];
          const float* crow = cb + (size_t)idx * DDIM;

          float rn[8];
          for (int j = 0; j < 8; ++j) rn[j] = crow[j] * crow[j];
          for (int i = 8; i < DDIM; i += 8)
            for (int j = 0; j < 8; ++j) rn[j] += crow[i + j] * crow[i + j];
          const float Nk =
              ((rn[0] + rn[1]) + (rn[2] + rn[3])) + ((rn[4] + rn[5]) + (rn[6] + rn[7]));

          double p64 = 0.0;
          for (int d = 0; d < DDIM; ++d) p64 += (double)xm[d] * (double)crow[d];
          const float pf = (float)p64;

          const float twop = 2.0f * pf;
          const float t1   = S - twop;
          const float Dv   = t1 + Nk;
          if (Dv < bestD || (Dv == bestD && idx < besti)) { bestD = Dv; besti = idx; }
        }
      }
    }
    widx[m] = besti;
  }
  __syncthreads();

  // ---- gather winners, write z_q (32-lane coalesced rows; cb L2-hot) ----
  {
    const int m = tid & 31, dg = tid >> 5;    // dg 0..7
    const int wi = widx[m];
    const float* crow = cb + (size_t)wi * DDIM;
    float* ob = out + (size_t)bb * (DDIM * 4096) + hw0;
#pragma unroll
    for (int p = 0; p < 8; ++p) {
      const int d = dg * 8 + p;
      ob[(size_t)d * 4096 + m] = crow[d];
    }
  }
}

extern "C" void kernel_launch(void* const* d_in, const int* in_sizes, int n_in,
                              void* d_out, int out_size, void* d_ws, size_t ws_size,
                              hipStream_t stream) {
  const float* ze = (const float*)d_in[0];    // [8,64,64,64]
  const float* cb = (const float*)d_in[1];    // [8192,64]
  float* hn = (float*)d_ws;                                     // 32 KB
  unsigned short* wcb = (unsigned short*)((char*)d_ws + 32768); // 1 MB frag-linear hi
  float* out = (float*)d_out;

  prep_kernel<<<NCH, 256, 0, stream>>>(cb, wcb, hn);
  vq_kernel<<<NTOK / MT, 256, 0, stream>>>(ze, cb, hn, wcb, out);
}

// Round 3
// 136.948 us; speedup vs baseline: 1.2593x; 1.2593x over previous
//
#include <hip/hip_runtime.h>
#include <float.h>

// Problem constants (fixed by reference: B=8, D=64, H=64, W=64, K=8192)
constexpr int KCODES = 8192;
constexpr int DDIM   = 64;
constexpr int NTOK   = 32768;
constexpr int MT     = 64;                 // tokens per WG (4 sets x 16)
constexpr int NSETS  = MT / 16;            // 4
constexpr int KC     = 64;                 // codes per chunk
constexpr int NCH    = KCODES / KC;        // 128 chunks
constexpr int CBCHUNK = KC * DDIM * 2;     // 8192 B (64 codes x 64 d x bf16, hi only)

constexpr int RQ    = 4;                   // LDS staging ring depth (per wave)
constexpr int ASLOT = 2048;                // per-wave A-frag bytes per chunk

typedef short v8s __attribute__((ext_vector_type(8)));
typedef float v4f __attribute__((ext_vector_type(4)));

static __device__ __forceinline__ unsigned short f2bf(float f) {
  union { float f; unsigned u; } v; v.f = f;
  return (unsigned short)((v.u + 0x7fffu + ((v.u >> 16) & 1u)) >> 16);  // RNE
}

// async global->LDS DMA: dest = wave-uniform LDS base + lane*16 (m104);
// source is per-lane. Tracked by vmcnt.
static __device__ __forceinline__ void dma16(const void* g, void* l) {
  __builtin_amdgcn_global_load_lds(
      (const __attribute__((address_space(1))) void*)g,
      (__attribute__((address_space(3))) void*)l, 16, 0, 0);
}

// ---- fused prep: bf16 hi codebook, FRAGMENT-LINEAR for mfma_16x16x32_bf16
// A-operand (A[m=lane&15][k=(lane>>4)*8+j]), + biased half-norms
// hn[k] = 0.5*||c_k||^2 + 2.0 (bias keeps phase-1 scores positive -> fp32
// bit pattern monotone for the packed-key argmin; scores land in [~0.7,~4.5]).
// Per chunk c: byte off = c*8192 + g*2048 + ks*1024 + lane*16 + j*2.
__global__ __launch_bounds__(256) void prep_kernel(
    const float* __restrict__ cb, unsigned short* __restrict__ wcb,
    float* __restrict__ hn) {
  const int c = blockIdx.x;                 // chunk 0..127
  const int tid = threadIdx.x;
  const int g = tid >> 6, lane = tid & 63;
  const int quad = lane >> 4, col = lane & 15;
  const int code = c * KC + g * 16 + col;
  const float* src = cb + (size_t)code * DDIM;
  float sq = 0.f;
#pragma unroll
  for (int ks = 0; ks < 2; ++ks) {
    v8s hi;
#pragma unroll
    for (int j = 0; j < 8; ++j) {
      const float x = src[ks * 32 + quad * 8 + j];
      sq += x * x;
      hi[j] = (short)f2bf(x);
    }
    const size_t b0 = ((size_t)c * CBCHUNK + g * 2048 + ks * 1024 + lane * 16) / 2;
    *reinterpret_cast<v8s*>(wcb + b0) = hi;
  }
  sq += __shfl_xor(sq, 16);
  sq += __shfl_xor(sq, 32);
  if (quad == 0) hn[code] = 0.5f * sq + 2.0f;
}

// Phase 1 (SCREEN): hi-only bf16 MFMA, score ~= hn - xh.ch.
//   Screening error e = xl.c + xh.cl: RMS ~2.5e-4, |e| <= ~2.8e-3 at 11
//   sigma. MT=64 tokens/WG (4 B-frag sets): 8 MFMAs per wave-chunk against
//   2 A-frag loads -- halves codebook L2 traffic (512 WGs x 1 MB) and
//   doubles MFMA:overhead vs MT=32. A-frags staged via async
//   global_load_lds into a PER-WAVE LDS ring (depth 4, 2 DMAs/chunk,
//   counted s_waitcnt vmcnt(6), no barriers in-loop: each wave stages and
//   reads only its own slice). hn staged ONCE into LDS (32 KB). 2 WG/CU.
//   Branchless packed-key top-2 per (lane,set) cell: key =
//   (score-bits & ~511) | (it*4 + r); floor quantization <= 512 ulp <= 2.4e-4.
// Phase 2: fast path when unique candidate within smin+8e-3. Proof: for any
//   candidate with stored > lim: true > stored - e > smin + 8e-3 - 2.8e-3;
//   smin >= true_min - e - 2.4e-4 -> true - true_min > 8e-3 - 5.6e-3 -
//   2.4e-4 > 2e-3 >> numpy's ulp(64) ~1.5e-5 quantization -> numpy cannot
//   prefer it. A numpy-winner distinct from the approx winner is itself
//   within lim -> cnt >= 2 -> refine. Refine = numpy-fp32-faithful decision
//   (pairwise-8 sums, D=fl(fl(S-2p)+N), correctly-rounded-fp64 p,
//   tie -> lowest index) — identical to all passing rounds.
__global__ __launch_bounds__(256, 2) void vq_kernel(
    const float* __restrict__ ze, const float* __restrict__ cb,
    const float* __restrict__ hn, const unsigned short* __restrict__ wcb,
    float* __restrict__ out) {
  // LDS map: [0,32768) per-wave staging ring (wave wv owns wv*RQ*ASLOT);
  //          [32768,65536) static hn copy. Epilogue arrays alias the ring
  //          after a drain + barrier.
  __shared__ __align__(16) char smem[65536];

  const int tid = threadIdx.x, lane = tid & 63, wv = tid >> 6;
  const int col = lane & 15, quad = lane >> 4;
  const int t0 = blockIdx.x * MT;
  const int bb = t0 >> 12, hw0 = t0 & 4095;   // 4096 % 64 == 0: one batch per WG
  const float* zb = ze + (size_t)bb * (DDIM * 4096) + hw0;

  // ---- one-time hn -> LDS copy (32 KB, 8 x float4 per thread) ----
  {
    v4f* dst = (v4f*)(smem + 32768);
    const v4f* src = (const v4f*)hn;
#pragma unroll
    for (int i = 0; i < 8; ++i) dst[tid + i * 256] = src[tid + i * 256];
  }

  // ---- B-frags: 4 sets x 16 tokens, negated bf16-hi, in registers.
  // B[k=(lane>>4)*8+j][n=lane&15]; token = s*16 + col; d = ks*32 + quad*8 + j.
  v8s nxh[NSETS][2];
#pragma unroll
  for (int s = 0; s < NSETS; ++s) {
    const int mtok = s * 16 + col;
#pragma unroll
    for (int ks = 0; ks < 2; ++ks) {
#pragma unroll
      for (int j = 0; j < 8; ++j) {
        const int d = ks * 32 + quad * 8 + j;
        nxh[s][ks][j] = (short)f2bf(-zb[(size_t)d * 4096 + mtok]);
      }
    }
  }

  char* wbase = smem + wv * (RQ * ASLOT);
  const char* wsrc = (const char*)wcb + wv * 2048 + lane * 16;
  const char* hns  = smem + 32768 + wv * 64 + quad * 16;  // this cell's hv

  // Stage chunk -> slot: 2x 16B-wide A DMAs (2 KB).
  auto stage = [&](int chunk, int slot) {
    const char* src = wsrc + (size_t)chunk * CBCHUNK;
    char* dst = wbase + slot * ASLOT;
    dma16(src, dst);
    dma16(src + 1024, dst + 1024);
  };

  unsigned m1[NSETS] = {0xFFFFFFFFu, 0xFFFFFFFFu, 0xFFFFFFFFu, 0xFFFFFFFFu};
  unsigned m2[NSETS] = {0xFFFFFFFFu, 0xFFFFFFFFu, 0xFFFFFFFFu, 0xFFFFFFFFu};

  auto compute = [&](const v8s (&A)[2], const v4f hv, int it) {
    const unsigned base9 = (unsigned)(it * 4);   // 9-bit cell-local index base
#pragma unroll
    for (int s = 0; s < NSETS; ++s) {            // 4 independent MFMA chains
      v4f acc = hv;
      acc = __builtin_amdgcn_mfma_f32_16x16x32_bf16(A[0], nxh[s][0], acc, 0, 0, 0);
      acc = __builtin_amdgcn_mfma_f32_16x16x32_bf16(A[1], nxh[s][1], acc, 0, 0, 0);
      unsigned k0 = (__float_as_uint(acc[0]) & ~511u) | (base9 + 0);
      unsigned k1 = (__float_as_uint(acc[1]) & ~511u) | (base9 + 1);
      unsigned k2 = (__float_as_uint(acc[2]) & ~511u) | (base9 + 2);
      unsigned k3 = (__float_as_uint(acc[3]) & ~511u) | (base9 + 3);
      const unsigned km = min(min(k0, k1), min(k2, k3));
      const unsigned old1 = m1[s];
      m1[s] = min(old1, km);
      m2[s] = min(m2[s], max(old1, km));   // branchless 2nd-best
    }
  };

  // hn LDS writes visible to all waves before any in-loop hv read.
  __syncthreads();

  // ---- airtight vmcnt ledger: drain prologue loads before first stage.
  asm volatile("s_waitcnt vmcnt(0)" ::: "memory");
  __builtin_amdgcn_sched_barrier(0);

#pragma unroll
  for (int r = 0; r < RQ; ++r) stage(r, r);   // 8 DMAs in flight

  for (int it = 0; it < NCH; ++it) {
    const int slot = it & (RQ - 1);
    // Wait until chunk `it`'s 2 DMAs landed (8 outstanding -> <= 6).
    asm volatile("s_waitcnt vmcnt(6)" ::: "memory");
    __builtin_amdgcn_sched_barrier(0);

    v8s A[2]; v4f hv;
    {
      const char* b = wbase + slot * ASLOT;
      A[0] = *reinterpret_cast<const v8s*>(b + lane * 16);
      A[1] = *reinterpret_cast<const v8s*>(b + 1024 + lane * 16);
      hv   = *reinterpret_cast<const v4f*>(hns + (size_t)it * 256);
    }
    compute(A, hv, it);

    // ds_reads of this slot fully retired before the DMA overwrite lands.
    asm volatile("s_waitcnt lgkmcnt(0)" ::: "memory");
    __builtin_amdgcn_sched_barrier(0);
    stage((it + RQ) & (NCH - 1), slot);   // wraps at tail: redundant, never read
  }

  // Drain in-flight DMAs, then all waves quiesce before aliasing LDS.
  asm volatile("s_waitcnt vmcnt(0)" ::: "memory");
  __syncthreads();

  float (*c_s1)[MT] = (float (*)[MT])(smem);             // 4 KB
  float (*c_s2)[MT] = (float (*)[MT])(smem + 4096);      // 4 KB
  int   (*c_i1)[MT] = (int (*)[MT])(smem + 8192);        // 4 KB
  int   (*c_i2)[MT] = (int (*)[MT])(smem + 12288);       // 4 KB
  int*   widx       = (int*)(smem + 16384);              // 256 B

  // ---- surface per-cell top-2 (cell = wv*4+quad; 16 cells x 512 codes) ----
  {
    const int cell = wv * 4 + quad;
#pragma unroll
    for (int s = 0; s < NSETS; ++s) {
      const int m = s * 16 + col;
      const unsigned K1 = m1[s], K2 = m2[s];
      c_s1[cell][m] = __uint_as_float(K1 & ~511u);
      c_s2[cell][m] = __uint_as_float(K2 & ~511u);
      // decode: local = it*4 + r -> code = it*64 + wv*16 + quad*4 + r
      c_i1[cell][m] = (int)((K1 & 511u) >> 2) * KC + wv * 16 + quad * 4 + (int)(K1 & 3u);
      c_i2[cell][m] = (int)((K2 & 511u) >> 2) * KC + wv * 16 + quad * 4 + (int)(K2 & 3u);
    }
  }
  __syncthreads();

  // ---- phase 2: fast path or numpy-faithful refine (wave 0, 1 token/lane) ----
  if (tid < MT) {
#pragma clang fp contract(off)   // numpy: separate mul then add; no FMA
    const int m = tid;

    float smin = FLT_MAX; int fidx = 0x7fffffff;
    for (int c = 0; c < 16; ++c) {
      const float a = c_s1[c][m];
      if (a < smin) { smin = a; fidx = c_i1[c][m]; }
    }
    const float lim = smin + 8e-3f;   // covers 2*e_screen(2.8e-3) + key floor
                                      // 2.4e-4 + numpy noise, ~1.4x slack
    int cnt = 0;
    for (int c = 0; c < 16; ++c) {
      cnt += (c_s1[c][m] <= lim);
      cnt += (c_s2[c][m] <= lim);
    }

    int besti;
    if (cnt == 1) {
      besti = fidx;   // unique in-margin candidate: approx argmin == numpy argmin
    } else {
      const float* xz = zb + m;
      float xm[DDIM];
      for (int d = 0; d < DDIM; ++d) xm[d] = xz[(size_t)d * 4096];

      float r[8];
      for (int j = 0; j < 8; ++j) r[j] = xm[j] * xm[j];
      for (int i = 8; i < DDIM; i += 8)
        for (int j = 0; j < 8; ++j) r[j] += xm[i + j] * xm[i + j];
      const float S = ((r[0] + r[1]) + (r[2] + r[3])) + ((r[4] + r[5]) + (r[6] + r[7]));

      float bestD = FLT_MAX;
      besti = 0x7fffffff;
      for (int c = 0; c < 16; ++c) {
        for (int h = 0; h < 2; ++h) {
          const float sp = h ? c_s2[c][m] : c_s1[c][m];
          if (sp > lim) continue;
          const int idx = h ? c_i2[c][m] : c_i1[c][m];
          const float* crow = cb + (size_t)idx * DDIM;

          float rn[8];
          for (int j = 0; j < 8; ++j) rn[j] = crow[j] * crow[j];
          for (int i = 8; i < DDIM; i += 8)
            for (int j = 0; j < 8; ++j) rn[j] += crow[i + j] * crow[i + j];
          const float Nk =
              ((rn[0] + rn[1]) + (rn[2] + rn[3])) + ((rn[4] + rn[5]) + (rn[6] + rn[7]));

          double p64 = 0.0;
          for (int d = 0; d < DDIM; ++d) p64 += (double)xm[d] * (double)crow[d];
          const float pf = (float)p64;

          const float twop = 2.0f * pf;
          const float t1   = S - twop;
          const float Dv   = t1 + Nk;
          if (Dv < bestD || (Dv == bestD && idx < besti)) { bestD = Dv; besti = idx; }
        }
      }
    }
    widx[m] = besti;
  }
  __syncthreads();

  // ---- gather winners, write z_q (64-lane coalesced rows; cb L2-hot) ----
  {
    const int m = tid & 63, dg = tid >> 6;    // dg 0..3
    const int wi = widx[m];
    const float* crow = cb + (size_t)wi * DDIM;
    float* ob = out + (size_t)bb * (DDIM * 4096) + hw0;
#pragma unroll
    for (int p = 0; p < 16; ++p) {
      const int d = dg * 16 + p;
      ob[(size_t)d * 4096 + m] = crow[d];
    }
  }
}

extern "C" void kernel_launch(void* const* d_in, const int* in_sizes, int n_in,
                              void* d_out, int out_size, void* d_ws, size_t ws_size,
                              hipStream_t stream) {
  const float* ze = (const float*)d_in[0];    // [8,64,64,64]
  const float* cb = (const float*)d_in[1];    // [8192,64]
  float* hn = (float*)d_ws;                                     // 32 KB
  unsigned short* wcb = (unsigned short*)((char*)d_ws + 32768); // 1 MB frag-linear hi
  float* out = (float*)d_out;

  prep_kernel<<<NCH, 256, 0, stream>>>(cb, wcb, hn);
  vq_kernel<<<NTOK / MT, 256, 0, stream>>>(ze, cb, hn, wcb, out);
}